// Round 11
// baseline (38.623 us; speedup 1.0000x reference)
//
#include <hip/hip_runtime.h>

#define T_STEPS 512
#define C_CH    128
#define U_LAB   48
#define PF      16
#define EPSF    (1e-7f)
#define SB0() __builtin_amdgcn_sched_barrier(0)

__device__ __forceinline__ float flog2(float x) {
#if __has_builtin(__builtin_amdgcn_logf)
    return __builtin_amdgcn_logf(x);    // v_log_f32 (log2)
#else
    return __builtin_log2f(x);
#endif
}

// DPP move, invalid lanes get old=0 (R9-proven pattern).
// ctrl: row_shr:N = 0x110|N, wave_shl:1 = 0x130, wave_shr:1 = 0x138
template <int CTRL>
__device__ __forceinline__ float dpp0(float x) {
    int r = __builtin_amdgcn_update_dpp(0, __builtin_bit_cast(int, x),
                                        CTRL, 0xF, 0xF, false);
    return __builtin_bit_cast(float, r);
}

__device__ __forceinline__ float rdlane(float x, int l) {
    return __builtin_bit_cast(float, __builtin_amdgcn_readlane(__builtin_bit_cast(int, x), l));
}

// Wave max via row_shr cascade + readlane of the 4 row results (R9-proven).
__device__ __forceinline__ float wave_max4(float v) {
    float mx = v;
    mx = fmaxf(mx, dpp0<0x111>(mx));
    mx = fmaxf(mx, dpp0<0x112>(mx));
    mx = fmaxf(mx, dpp0<0x114>(mx));
    mx = fmaxf(mx, dpp0<0x118>(mx));   // lanes 15/31/47/63 = per-row maxes
    float m01 = fmaxf(rdlane(mx, 15), rdlane(mx, 31));
    float m23 = fmaxf(rdlane(mx, 47), rdlane(mx, 63));
    return fmaxf(m01, m23);
}

// Renormalize so wave max's exponent field ~= TGT_FIELD (exact pow-2, clamped).
// Invariant: true = stored * 2^cum.  TGT=190 -> max ~2^63 (headroom band).
template <int TGT_FIELD>
__device__ __forceinline__ void rescale2(float& a0, float& a1, int& cum) {
    float m  = wave_max4(fmaxf(a0, a1));
    int   E  = (__builtin_bit_cast(int, m) >> 23) & 0xFF;
    int   f  = TGT_FIELD + 127 - E;
    f = (f < 1) ? 1 : (f > 254 ? 254 : f);
    cum -= f - 127;
    float sc = __builtin_bit_cast(float, f << 23);
    a0 *= sc; a1 *= sc;
}

// BISECT: both waves run FULL-T linear arms. Even b scored by forward (wave 0),
// odd b scored by backward (wave 1). Lane t owns s=2t (a0) / s=2t+1 (a1).
__global__ __launch_bounds__(128) void ctc_bisect_kernel(const int* __restrict__ yt,
                                                         const float* __restrict__ yp,
                                                         float* __restrict__ out) {
    const int b    = blockIdx.x;
    const int lane = threadIdx.x & 63;
    const int wav  = threadIdx.x >> 6;

    const bool is_lab = (lane < U_LAB);
    const int  lab    = is_lab ? yt[b * U_LAB + lane] : 0;
    const float* __restrict__ base = yp + (size_t)b * T_STEPS * C_CH;
    const float* pB = base + (C_CH - 1);
    const float* pL = base + lab;

    float a0, a1;
    int   cum = 0;

    if (wav == 0) {
        // ---------------- forward: alpha, t = 0 .. 511 ----------------
        int labprev = __builtin_amdgcn_update_dpp(-1, lab, 0x138, 0xF, 0xF, false);
        const bool allow = (lane >= 1) && is_lab && (lab != labprev);

        {
            float pb0 = base[C_CH - 1] + EPSF;
            float pl0 = base[lab] + EPSF;
            a0 = (lane == 0) ? pb0 : 0.0f;
            a1 = (lane == 0) ? pl0 : 0.0f;
        }
        rescale2<190>(a0, a1, cum);             // lift into headroom band

        float curB[PF], curL[PF];
#pragma unroll
        for (int k = 0; k < PF; ++k) {          // preload rows 1..16
            curB[k] = pB[(size_t)(1 + k) * C_CH];
            curL[k] = pL[(size_t)(1 + k) * C_CH];
        }
        SB0();

#define FWD_STEP(k)  do { \
            float pb2 = curB[k] + EPSF; \
            float pl2 = is_lab ? (curL[k] + EPSF) : 0.0f; \
            float p1  = dpp0<0x138>(a1);                 /* alpha[2t-1] */ \
            float s3  = a1 + a0 + (allow ? p1 : 0.0f); \
            a0 = (a0 + p1) * pb2; \
            a1 = s3 * pl2; \
        } while (0)

        int t0 = 1;
#pragma unroll 1
        for (int body = 0; body < 31; ++body) {   // t = 1..496
#pragma unroll
            for (int k = 0; k < PF; ++k) {
                FWD_STEP(k);
                int tn = t0 + k + PF; tn = (tn < T_STEPS - 1) ? tn : (T_STEPS - 1);
                curB[k] = pB[(size_t)tn * C_CH];
                curL[k] = pL[(size_t)tn * C_CH];
                SB0();
                if ((k & 3) == 3) rescale2<190>(a0, a1, cum);
            }
            t0 += PF;
        }
        // tail: t = 497..511 (slots 0..14)
#pragma unroll
        for (int k = 0; k < PF - 1; ++k) {
            FWD_STEP(k);
            if ((k & 3) == 3) rescale2<190>(a0, a1, cum);
        }

        // score at stored (2^63) scale: NO final renorm (log handles the scale)
        float v96 = __shfl(a0, 48);
        float v95 = __shfl(a1, 47);
        float ll2 = flog2(v95 + v96) + (float)cum;
        if (((b & 1) == 0) && lane == 0)
            out[b] = -(ll2 * 0.69314718055994530942f);
        else
            asm volatile("" :: "v"(ll2));
    } else {
        // ---------------- backward: betaE, t = 511 .. 0 ----------------
        int labnext = (lane + 1 < U_LAB) ? yt[b * U_LAB + lane + 1] : -1;
        const bool allowD = (lane + 1 < U_LAB) && (lab != labnext);

        {
            const float* row = base + (size_t)(T_STEPS - 1) * C_CH;
            float pb0 = row[C_CH - 1] + EPSF;
            float pl0 = row[lab] + EPSF;
            a0 = (lane == 48) ? pb0 : 0.0f;   // state 96 (last blank)
            a1 = (lane == 47) ? pl0 : 0.0f;   // state 95 (last label)
        }
        rescale2<190>(a0, a1, cum);             // lift into headroom band

        float curB[PF], curL[PF];
#pragma unroll
        for (int k = 0; k < PF; ++k) {          // preload rows 510..495
            curB[k] = pB[(size_t)(510 - k) * C_CH];
            curL[k] = pL[(size_t)(510 - k) * C_CH];
        }
        SB0();

#define BWD_STEP(k)  do { \
            float pb2 = curB[k] + EPSF; \
            float pl2 = is_lab ? (curL[k] + EPSF) : 0.0f; \
            float b0  = dpp0<0x130>(a0);                 /* betaE[s+1] */ \
            float b1  = dpp0<0x130>(a1);                 /* betaE[s+2] */ \
            float s3  = a1 + b0 + (allowD ? b1 : 0.0f); \
            a0 = (a0 + a1) * pb2; \
            a1 = s3 * pl2; \
        } while (0)

        int t0 = 510;
#pragma unroll 1
        for (int body = 0; body < 31; ++body) {   // t = 510..15
#pragma unroll
            for (int k = 0; k < PF; ++k) {
                BWD_STEP(k);
                int tn = t0 - k - PF; tn = (tn > 0) ? tn : 0;
                curB[k] = pB[(size_t)tn * C_CH];
                curL[k] = pL[(size_t)tn * C_CH];
                SB0();
                if ((k & 3) == 3) rescale2<190>(a0, a1, cum);
            }
            t0 -= PF;
        }
        // tail: t = 14..0 (slots 0..14)
#pragma unroll
        for (int k = 0; k < PF - 1; ++k) {
            BWD_STEP(k);
            if ((k & 3) == 3) rescale2<190>(a0, a1, cum);
        }

        // score: P = betaE_0(0) + betaE_0(1)  (both live in lane 0)
        float w0 = __shfl(a0, 0);
        float w1 = __shfl(a1, 0);
        float ll2 = flog2(w0 + w1) + (float)cum;
        if (((b & 1) == 1) && lane == 0)
            out[b] = -(ll2 * 0.69314718055994530942f);
        else
            asm volatile("" :: "v"(ll2));
    }
}

extern "C" void kernel_launch(void* const* d_in, const int* in_sizes, int n_in,
                              void* d_out, int out_size, void* d_ws, size_t ws_size,
                              hipStream_t stream) {
    const int*   yt  = (const int*)d_in[0];   // y_true [B, 48] int
    const float* yp  = (const float*)d_in[1]; // y_pred [B, 512, 128] f32
    float*       out = (float*)d_out;         // [B, 1] f32
    const int B = in_sizes[0] / U_LAB;        // 256
    ctc_bisect_kernel<<<B, 128, 0, stream>>>(yt, yp, out);
}